// Round 14
// baseline (340.217 us; speedup 1.0000x reference)
//
#include <hip/hip_runtime.h>
#include <math.h>

#define BB 4
#define NN 4995
#define CC 128
#define IMG 224
#define IMGP (IMG*IMG)
#define ALPHA_F 100.0f
#define SPLITS 8
#define COLS_PER_SPLIT 640   // 32-aligned; 8*640=5120 >= 4995
#define RBLK 40              // ceil(4995/128)
#define NG 158               // col groups of 32 (incl. 1 pad group)
#define NGP 160              // c2q pad coverage groups
#define NCP 5120             // padded col count for c2q
#define NTAP (2*BB*NN*25)    // 999000 scatter taps
#define NREP 4
#define NREP8 8
#define TKCAP 256            // per-row candidate cap (16-bit radix over-selects slightly)

// softmax scale folding: (ALPHA * log2(e))^2 ; p = sqrt(SCALE*d) = ALPHA*log2e*sqrt(d)
#define SM_SCALE 20813.6898f
#define NEG2S   -41627.3796f
#define EPS_S    2.08136898e-8f   // 1e-12 * SM_SCALE

// ws layout in float units
#define OFF_V12    0            // 59940
#define OFF_FN1    60000        // 19980 (scaled by SM_SCALE)
#define OFF_V1Q    81000        // 79920 {x,y,z,|v1|^2}
#define OFF_V2Q    161000       // 79920 {x,y,z,|v2|^2}
#define OFF_C2Q    241000       // 81920 padded [b][5120] {x,y,z,SM_SCALE*|f2|^2}; pad={0,0,0,1e30}
#define OFF_PART   323000       // 19980*8*5 = 799200 -> ends 1122200
#define OFF_IMG1   1123000      // 200704
#define OFF_IMG2   1323704      // 200704 -> ends 1524408
#define OFF_ACC    1524408      // 3*64 f64 = 384 floats (byte 6097632, 8-aligned)
#define OFF_STATS  1524792      // 128 -> ends 1524920
#define OFF_F2H    1525000      // 4*158*4096 shorts = 1294336 floats
#define OFF_F2L    2820000      // 1294336 floats -> ends 4114336 (16.46MB)
#define OFF_IMGR   4115000      // up to 8 reps * 2 imgs * 4 b * 50176 = 3211264 floats -> ends 7326264
#define WS_NEED_REP  ((size_t)5721000*sizeof(float))   // 4 replicas
#define WS_NEED_REP8 ((size_t)7327000*sizeof(float))   // 8 replicas
#define ZERO_START OFF_IMG1
#define ZERO_FLOATS (1524920 - OFF_IMG1)
#define ZERO2_FLOATS (1524920 - OFF_ACC)   // ACC+STATS = 512

typedef short v8s  __attribute__((ext_vector_type(8)));
typedef float v16f __attribute__((ext_vector_type(16)));

#if __has_builtin(__builtin_amdgcn_exp2f)
__device__ __forceinline__ float fast_exp2(float x){ return __builtin_amdgcn_exp2f(x); }
#else
__device__ __forceinline__ float fast_exp2(float x){ float r; asm("v_exp_f32 %0, %1" : "=v"(r) : "v"(x)); return r; }
#endif
#if __has_builtin(__builtin_amdgcn_sqrtf)
__device__ __forceinline__ float fast_sqrt(float x){ return __builtin_amdgcn_sqrtf(x); }
#else
__device__ __forceinline__ float fast_sqrt(float x){ float r; asm("v_sqrt_f32 %0, %1" : "=v"(r) : "v"(x)); return r; }
#endif

__device__ __forceinline__ float wave_min(float v){
#pragma unroll
  for (int off=32; off; off>>=1) v = fminf(v, __shfl_xor(v, off));
  return v;
}
__device__ __forceinline__ float wave_sum(float v){
#pragma unroll
  for (int off=32; off; off>>=1) v += __shfl_xor(v, off);
  return v;
}

// pack top-16 bits (bf16 truncation) of two floats: (hi16(b)<<16)|hi16(a)
__device__ __forceinline__ int pack_bf_hi(float a, float b){
  return (int)__builtin_amdgcn_perm(__float_as_uint(b), __float_as_uint(a), 0x07060302u);
}

__device__ __forceinline__ void cvt_hilo(float4 a, float4 c, int4& hi, int4& lo){
  float hx=__uint_as_float(__float_as_uint(a.x)&0xffff0000u);
  float hy=__uint_as_float(__float_as_uint(a.y)&0xffff0000u);
  float hz=__uint_as_float(__float_as_uint(a.z)&0xffff0000u);
  float hw=__uint_as_float(__float_as_uint(a.w)&0xffff0000u);
  float gx=__uint_as_float(__float_as_uint(c.x)&0xffff0000u);
  float gy=__uint_as_float(__float_as_uint(c.y)&0xffff0000u);
  float gz=__uint_as_float(__float_as_uint(c.z)&0xffff0000u);
  float gw=__uint_as_float(__float_as_uint(c.w)&0xffff0000u);
  hi = make_int4(pack_bf_hi(a.x,a.y), pack_bf_hi(a.z,a.w),
                 pack_bf_hi(c.x,c.y), pack_bf_hi(c.z,c.w));
  lo = make_int4(pack_bf_hi(a.x-hx,a.y-hy), pack_bf_hi(a.z-hz,a.w-hw),
                 pack_bf_hi(c.x-gx,c.y-gy), pack_bf_hi(c.z-gz,c.w-gw));
}

__device__ __forceinline__ v8s i4_to_s8(int4 v){
  union { int4 i; v8s s; } u; u.i = v; return u.s;
}

// async global->LDS, 16B per lane, dest = wave-uniform base + lane*16
__device__ __forceinline__ void gld_lds16(const void* g, void* l){
  __builtin_amdgcn_global_load_lds((const __attribute__((address_space(1))) void*)g,
                                   (__attribute__((address_space(3))) void*)l, 16, 0, 0);
}

// monotone float->uint order map
__device__ __forceinline__ unsigned int fkey(float f){
  unsigned int u = __float_as_uint(f);
  return ((int)u < 0) ? ~u : (u ^ 0x80000000u);
}

// ---------------- fused: feat2->bf16 hi/lo tiles + c2q (+pads) + feat1 norms + vert quads ----------------
// tile layout [b][g][kt4][kh2][half2][c32][j8], strides (shorts): j=1,c32=8,half=256,kh=512,kt=1024,g=4096
__global__ __launch_bounds__(256) void k_conv(const float* __restrict__ feat1,
                                              const float* __restrict__ feat2,
                                              const float* __restrict__ verts1,
                                              const float* __restrict__ verts2,
                                              float* __restrict__ ws) {
  __shared__ float s2p[8][32], s1p[8][32];
  int g = blockIdx.x, b = blockIdx.y;
  int t = threadIdx.x;
  if (g >= NG){   // pure pad groups (158,159): only c2q pads
    if (t < 32){
      int c = g*32 + t;
      if (c < NCP)
        ((float4*)(ws+OFF_C2Q))[(size_t)b*NCP + c] = make_float4(0.f,0.f,0.f,1e30f);
    }
    return;
  }
  int q = t >> 5, c32 = t & 31;
  int col = g*32 + c32; if (col > NN-1) col = NN-1;
  const float4* src = (const float4*)(feat2 + ((size_t)(b*NN + col))*CC) + q*4;
  float4 v0 = src[0], v1 = src[1], v2 = src[2], v3 = src[3];
  {
    float s2 = 0.f;
    s2=fmaf(v0.x,v0.x,s2); s2=fmaf(v0.y,v0.y,s2); s2=fmaf(v0.z,v0.z,s2); s2=fmaf(v0.w,v0.w,s2);
    s2=fmaf(v1.x,v1.x,s2); s2=fmaf(v1.y,v1.y,s2); s2=fmaf(v1.z,v1.z,s2); s2=fmaf(v1.w,v1.w,s2);
    s2=fmaf(v2.x,v2.x,s2); s2=fmaf(v2.y,v2.y,s2); s2=fmaf(v2.z,v2.z,s2); s2=fmaf(v2.w,v2.w,s2);
    s2=fmaf(v3.x,v3.x,s2); s2=fmaf(v3.y,v3.y,s2); s2=fmaf(v3.z,v3.z,s2); s2=fmaf(v3.w,v3.w,s2);
    s2p[q][c32] = s2;
  }
  {
    const float4* fa = (const float4*)(feat1 + ((size_t)(b*NN + col))*CC) + q*4;
    float4 u0 = fa[0], u1 = fa[1], u2 = fa[2], u3 = fa[3];
    float s1 = 0.f;
    s1=fmaf(u0.x,u0.x,s1); s1=fmaf(u0.y,u0.y,s1); s1=fmaf(u0.z,u0.z,s1); s1=fmaf(u0.w,u0.w,s1);
    s1=fmaf(u1.x,u1.x,s1); s1=fmaf(u1.y,u1.y,s1); s1=fmaf(u1.z,u1.z,s1); s1=fmaf(u1.w,u1.w,s1);
    s1=fmaf(u2.x,u2.x,s1); s1=fmaf(u2.y,u2.y,s1); s1=fmaf(u2.z,u2.z,s1); s1=fmaf(u2.w,u2.w,s1);
    s1=fmaf(u3.x,u3.x,s1); s1=fmaf(u3.y,u3.y,s1); s1=fmaf(u3.z,u3.z,s1); s1=fmaf(u3.w,u3.w,s1);
    s1p[q][c32] = s1;
  }
  short* f2h = (short*)(ws + OFF_F2H);
  short* f2l = (short*)(ws + OFF_F2L);
  size_t base = ((size_t)(b*NG + g))*4096 + (size_t)q*512 + c32*8;
  int4 hi, lo;
  cvt_hilo(v0, v1, hi, lo);
  *(int4*)&f2h[base] = hi;  *(int4*)&f2l[base] = lo;
  cvt_hilo(v2, v3, hi, lo);
  *(int4*)&f2h[base + 256] = hi;  *(int4*)&f2l[base + 256] = lo;
  __syncthreads();
  if (t < 32){
    int c = g*32 + t;
    if (c < NN){
      float S2 = ((s2p[0][t]+s2p[1][t])+(s2p[2][t]+s2p[3][t]))
               + ((s2p[4][t]+s2p[5][t])+(s2p[6][t]+s2p[7][t]));
      float S1 = ((s1p[0][t]+s1p[1][t])+(s1p[2][t]+s1p[3][t]))
               + ((s1p[4][t]+s1p[5][t])+(s1p[6][t]+s1p[7][t]));
      size_t r = (size_t)(b*NN + c);
      float x=verts1[r*3], y=verts1[r*3+1], z=verts1[r*3+2];
      ((float4*)(ws+OFF_V1Q))[r] = make_float4(x,y,z, x*x+y*y+z*z);
      float x2=verts2[r*3], y2=verts2[r*3+1], z2=verts2[r*3+2];
      ((float4*)(ws+OFF_V2Q))[r] = make_float4(x2,y2,z2, x2*x2+y2*y2+z2*z2);
      ((float4*)(ws+OFF_C2Q))[(size_t)b*NCP + c] = make_float4(x2,y2,z2, SM_SCALE*S2);
      ws[OFF_FN1+r] = SM_SCALE*S1;
    } else if (c < NCP){
      ((float4*)(ws+OFF_C2Q))[(size_t)b*NCP + c] = make_float4(0.f,0.f,0.f,1e30f);
    }
  }
}

// ---------------- stage A: R7-champion structure (118.8us measured) ----------------
// 2-buffer dbuf K-loop with __syncthreads drain, colq 12KB in LDS, SPLITS=8.
// v14: setprio removed (lockstep barrier structure -> T5 inapplicable per m190).
__global__ __launch_bounds__(256) void k_stageA(const float* __restrict__ feat1,
      float* __restrict__ ws) {
  __shared__ __align__(16) short Bbuf[2][4096];   // per buf: Bh[0..2047] | Bl[2048..4095]
  __shared__ __align__(16) float colq[768*4];     // 640 used (+pad), {x,y,z,SM_SCALE*|f2|^2}

  int rblk  = blockIdx.x;
  int split = blockIdx.y;
  int b     = blockIdx.z;
  int rowBase = rblk*128;
  int colBase = split*COLS_PER_SPLIT;
  int colEnd  = colBase + COLS_PER_SPLIT; if (colEnd > NN) colEnd = NN;
  int nct = (colEnd - colBase + 63) >> 6;
  int nst = nct << 2;

  int t    = threadIdx.x;
  int w    = t >> 6;
  int lane = t & 63;
  int half = lane >> 5;
  int m32  = lane & 31;

  const float* f1b = feat1 + (size_t)b*NN*CC;
  const short* f2h = (const short*)(ws + OFF_F2H);
  const short* f2l = (const short*)(ws + OFF_F2L);
  const float4* cqb = (const float4*)(ws + OFF_C2Q) + (size_t)b*NCP;

  // --- stage colq for the whole split: 3 rounds x 256 lanes x 16B (padded c2q, clamp only) ---
#pragma unroll
  for (int r=0; r<3; r++){
    int col = colBase + r*256 + t; if (col > NCP-1) col = NCP-1;
    gld_lds16(cqb + col, &colq[(r*256 + w*64)*4]);
  }

  // per-lane source offset into f2h/f2l (shorts); wave w covers quarter of the 2KB-tile pair
  size_t f2base = (((size_t)(b*NG) + (colBase>>5) + (w>>1)) << 12) + (size_t)((t&127)*8);

  // --- stage B tile s=0 ---
  {
    short* d = &Bbuf[0][0] + w*512;
    gld_lds16(f2h + f2base, d);
    gld_lds16(f2l + f2base, d + 2048);
  }

  // --- A fragments: 64 floats of own feat1 row, converted once to bf16 hi/lo ---
  int nrow = rowBase + w*32 + m32;
  int nclamp = nrow > NN-1 ? NN-1 : nrow;
  float sn = ws[OFF_FN1 + (size_t)b*NN + nclamp];   // SM_SCALE*|f1|^2
  const float4* ar = (const float4*)(f1b + (size_t)nclamp*CC) + (half<<1);
  v8s Afh[8], Afl[8];   // slot = kt*2+kh
#pragma unroll
  for (int sl=0; sl<8; ++sl){
    float4 v0 = ar[sl*4], v1 = ar[sl*4+1];
    int4 hi, lo;
    cvt_hilo(v0, v1, hi, lo);
    Afh[sl] = i4_to_s8(hi); Afl[sl] = i4_to_s8(lo);
  }

  __syncthreads();   // drains vmcnt: colq + stage(0) complete for all waves

  // min-domain online softmax state: mm = running min of p = ALPHA*log2e*sqrt(d)
  float mm = INFINITY, S = 0.f, Vx = 0.f, Vy = 0.f, Vz = 0.f;

  for (int ci = 0; ci < nct; ci++){
    v16f acc0, acc1;
#pragma unroll
    for (int i=0;i<16;i++){ acc0[i]=0.f; acc1[i]=0.f; }

#pragma unroll
    for (int kt = 0; kt < 4; kt++){
      int s = (ci<<2) + kt;
      // prefetch next tile into the other buffer
      if (s+1 < nst){
        int s1 = s+1;
        size_t so = f2base + ((size_t)(s1>>2)<<13) + ((size_t)(s1&3)<<10);
        short* d = &Bbuf[0][0] + ((s1&1)<<12) + w*512;
        gld_lds16(f2h + so, d);
        gld_lds16(f2l + so, d + 2048);
      }
      const short* Bh = &Bbuf[0][0] + ((s&1)<<12);
      const short* Bl = Bh + 2048;
#pragma unroll
      for (int kh=0; kh<2; kh++){
        int fo = (kh<<9) + (half<<8) + (m32<<3);
        v8s a0h = *(const v8s*)&Bh[fo];
        v8s a0l = *(const v8s*)&Bl[fo];
        v8s a1h = *(const v8s*)&Bh[1024+fo];
        v8s a1l = *(const v8s*)&Bl[1024+fo];
        v8s b1h = Afh[kt*2+kh];
        v8s b1l = Afl[kt*2+kh];
        acc0 = __builtin_amdgcn_mfma_f32_32x32x16_bf16(a0h, b1h, acc0, 0,0,0);
        acc0 = __builtin_amdgcn_mfma_f32_32x32x16_bf16(a0h, b1l, acc0, 0,0,0);
        acc0 = __builtin_amdgcn_mfma_f32_32x32x16_bf16(a0l, b1h, acc0, 0,0,0);
        acc1 = __builtin_amdgcn_mfma_f32_32x32x16_bf16(a1h, b1h, acc1, 0,0,0);
        acc1 = __builtin_amdgcn_mfma_f32_32x32x16_bf16(a1h, b1l, acc1, 0,0,0);
        acc1 = __builtin_amdgcn_mfma_f32_32x32x16_bf16(a1l, b1h, acc1, 0,0,0);
      }
      __syncthreads();   // lgkm drained by MFMA deps; vmcnt(0)+barrier makes next buf ready
    }

    // --- epilogue: p = sqrt(SM_SCALE*d) (log2-domain logit magnitude), min-track ---
    int cb4 = ci<<8;   // float index base into colq = ci*64*4
    float Mt = INFINITY;
#pragma unroll
    for (int reg=0; reg<16; reg++){
      int cp0 = (reg&3) + 8*(reg>>2) + 4*half;
      float f0 = colq[cb4 + cp0*4 + 3];
      float d0 = fmaf(NEG2S, acc0[reg], sn) + f0;
      float p0 = fast_sqrt(fmaxf(d0, EPS_S));
      acc0[reg] = p0; Mt = fminf(Mt, p0);
      float f1v = colq[cb4 + (cp0+32)*4 + 3];
      float d1 = fmaf(NEG2S, acc1[reg], sn) + f1v;
      float p1 = fast_sqrt(fmaxf(d1, EPS_S));
      acc1[reg] = p1; Mt = fminf(Mt, p1);
    }
    float mn = fminf(mm, Mt);
    float sc = fast_exp2(mn - mm);   // first tile: exp2(-inf) = 0
    float se=0.f, sx=0.f, sy=0.f, sz=0.f;
#pragma unroll
    for (int reg=0; reg<16; reg++){
      int cp0 = (reg&3) + 8*(reg>>2) + 4*half;
      float4 q0 = *(const float4*)&colq[cb4 + cp0*4];
      float e0 = fast_exp2(mn - acc0[reg]);
      se += e0; sx=fmaf(e0,q0.x,sx); sy=fmaf(e0,q0.y,sy); sz=fmaf(e0,q0.z,sz);
      float4 q1 = *(const float4*)&colq[cb4 + (cp0+32)*4];
      float e1 = fast_exp2(mn - acc1[reg]);
      se += e1; sx=fmaf(e1,q1.x,sx); sy=fmaf(e1,q1.y,sy); sz=fmaf(e1,q1.z,sz);
    }
    S  = fmaf(S,  sc, se);
    Vx = fmaf(Vx, sc, sx);
    Vy = fmaf(Vy, sc, sy);
    Vz = fmaf(Vz, sc, sz);
    mm = mn;
  }

  {
    float m2  = __shfl_xor(mm, 32);
    float S2  = __shfl_xor(S,  32);
    float Vx2 = __shfl_xor(Vx, 32);
    float Vy2 = __shfl_xor(Vy, 32);
    float Vz2 = __shfl_xor(Vz, 32);
    float M = fminf(mm, m2);
    float c1 = fast_exp2(M - mm), c2 = fast_exp2(M - m2);
    float Sf  = S*c1  + S2*c2;
    float Vxf = Vx*c1 + Vx2*c2;
    float Vyf = Vy*c1 + Vy2*c2;
    float Vzf = Vz*c1 + Vz2*c2;
    if (half==0 && nrow < NN){
      float* p = ws + OFF_PART + ((size_t)(b*NN+nrow)*SPLITS + split)*5;
      p[0]=M; p[1]=Sf; p[2]=Vxf; p[3]=Vyf; p[4]=Vzf;
    }
  }
}

// ---------------- self-rec (with inlined combine): 8 rows/wave, 32 rows/block ----------------
__global__ __launch_bounds__(256) void k_selfrec(float* __restrict__ ws) {
  __shared__ float v12s[32][3];
  int rblk = blockIdx.x, b = blockIdx.y;
  int t = threadIdx.x;
  int lane = t & 63, w = t >> 6;
  int r0blk = rblk*32;

  // inline combine (exact k_combine math/order) for this block's 32 rows
  if (t < 32){
    int row = r0blk + t;
    int rowc = row > NN-1 ? NN-1 : row;
    const float* p = ws + OFF_PART + (size_t)(b*NN+rowc)*SPLITS*5;
    float mm = INFINITY;
#pragma unroll
    for (int s=0;s<SPLITS;s++) mm = fminf(mm, p[s*5]);
    float S=0.f,Vx=0.f,Vy=0.f,Vz=0.f;
#pragma unroll
    for (int s=0;s<SPLITS;s++){
      float sc = fast_exp2(mm - p[s*5]);
      S  += p[s*5+1]*sc; Vx += p[s*5+2]*sc; Vy += p[s*5+3]*sc; Vz += p[s*5+4]*sc;
    }
    float ox = Vx/S, oy = Vy/S, oz = Vz/S;
    v12s[t][0]=ox; v12s[t][1]=oy; v12s[t][2]=oz;
    if (row < NN){
      ws[OFF_V12+(size_t)(b*NN+row)*3+0]=ox;
      ws[OFF_V12+(size_t)(b*NN+row)*3+1]=oy;
      ws[OFF_V12+(size_t)(b*NN+row)*3+2]=oz;
    }
  }
  __syncthreads();

  int r0 = r0blk + w*8;
  const float4* v2q = (const float4*)(ws + OFF_V2Q) + (size_t)b*NN;
  float xr[8], yr[8], zr[8], sar[8]; bool val[8];
#pragma unroll
  for (int j=0;j<8;j++){
    int n = r0+j; val[j] = (n < NN);
    int li = w*8+j;
    float x=v12s[li][0], y=v12s[li][1], z=v12s[li][2];
    sar[j]=x*x+y*y+z*z;
    xr[j]=-2.0f*x; yr[j]=-2.0f*y; zr[j]=-2.0f*z;
  }
  float mn[8];
#pragma unroll
  for (int j=0;j<8;j++) mn[j] = INFINITY;
  for (int m=lane; m<NN; m+=64) {
    float4 q = v2q[m];
#pragma unroll
    for (int j=0;j<8;j++)
      mn[j] = fminf(mn[j], fmaf(xr[j],q.x, fmaf(yr[j],q.y, fmaf(zr[j],q.z, q.w))));
  }
  float s = 0.f;
#pragma unroll
  for (int j=0;j<8;j++){
    float v = wave_min(mn[j]);
    s += val[j] ? (v + sar[j]) : 0.f;
  }
  if (lane==0)
    atomicAdd(((double*)(ws+OFF_ACC)) + ((rblk*4 + w) & 63), (double)s);
}

// ---------------- top-k v3: low-VGPR gated rescan, per-wave 16-bit radix ----------------
__global__ __launch_bounds__(256) void k_topk(const float* __restrict__ feat1,
        const int* __restrict__ kptr, float* __restrict__ ws) {
  __shared__ unsigned int keybuf[4*256];          // per-row 16-bit thread-min keys
  __shared__ unsigned long long cand[4*TKCAP];    // per-row candidates
  __shared__ int scnt[4];
  __shared__ float tfs[4];
  __shared__ int sel[4][16];
  __shared__ float rs[4];
  int t = threadIdx.x;
  int lane = t & 63, wid = t >> 6;
  int b = blockIdx.y;
  int n0 = blockIdx.x*4;
  int kk = *kptr; if (kk > 16) kk = 16; if (kk < 1) kk = 1;

  const float4* v1q = (const float4*)(ws + OFF_V1Q) + (size_t)b*NN;
  float mx[4], my2[4], mz[4];
#pragma unroll
  for (int j=0;j<4;j++){
    int n = n0+j; if (n > NN-1) n = NN-1;
    float4 me = v1q[n];
    mx[j]=-2.0f*me.x; my2[j]=-2.0f*me.y; mz[j]=-2.0f*me.z;
  }
  if (t < 4) scnt[t] = 0;

  // phase 1: per-thread min of e2 = |q|^2 - 2 p.q per row (no storage; sa is a per-row const)
  float mn[4] = {INFINITY, INFINITY, INFINITY, INFINITY};
  for (int i=0;i<20;i++){
    int m = t + 256*i;
    if (m < NN){
      float4 q = v1q[m];
#pragma unroll
      for (int j=0;j<4;j++){
        float d = fmaf(mx[j], q.x, fmaf(my2[j], q.y, fmaf(mz[j], q.z, q.w)));
        mn[j] = fminf(mn[j], d);
      }
    }
  }

#pragma unroll
  for (int j=0;j<4;j++)
    keybuf[j*256 + t] = fkey(mn[j]) >> 16;
  __syncthreads();

  // per-wave 16-bit ballot radix: wave wid computes row wid's threshold
  {
    unsigned int k0 = keybuf[wid*256 + lane];
    unsigned int k1 = keybuf[wid*256 + 64 + lane];
    unsigned int k2 = keybuf[wid*256 + 128 + lane];
    unsigned int k3 = keybuf[wid*256 + 192 + lane];
    unsigned int prefix = 0;
    for (int bit=15; bit>=0; --bit){
      unsigned int piv = prefix | (1u<<bit);
      int c = __popcll(__ballot(k0 < piv)) + __popcll(__ballot(k1 < piv))
            + __popcll(__ballot(k2 < piv)) + __popcll(__ballot(k3 < piv));
      if (c < kk) prefix = piv;
    }
    unsigned int K = (prefix<<16) | 0xFFFFu;     // full-key upper bound for the bucket
    unsigned int fb = (K & 0x80000000u) ? (K ^ 0x80000000u) : ~K;
    if (lane==0) tfs[wid] = __uint_as_float(fb);
  }
  __syncthreads();
  float tf0 = tfs[0], tf1 = tfs[1], tf2 = tfs[2], tf3 = tfs[3];

  // phase 2: gated rescan — only threads whose min passed the threshold
  bool g0 = (mn[0] <= tf0), g1 = (mn[1] <= tf1), g2 = (mn[2] <= tf2), g3 = (mn[3] <= tf3);
  if (g0|g1|g2|g3){
    for (int i=0;i<20;i++){
      int m = t + 256*i;
      if (m < NN){
        float4 q = v1q[m];
        float sw = q.w;
        float d0 = fmaf(mx[0], q.x, fmaf(my2[0], q.y, fmaf(mz[0], q.z, sw)));
        float d1 = fmaf(mx[1], q.x, fmaf(my2[1], q.y, fmaf(mz[1], q.z, sw)));
        float d2 = fmaf(mx[2], q.x, fmaf(my2[2], q.y, fmaf(mz[2], q.z, sw)));
        float d3 = fmaf(mx[3], q.x, fmaf(my2[3], q.y, fmaf(mz[3], q.z, sw)));
        if (g0 && d0 <= tf0){
          int pos = atomicAdd(&scnt[0], 1);
          if (pos < TKCAP) cand[0*TKCAP + pos] = ((unsigned long long)fkey(d0) << 13) | (unsigned int)m;
        }
        if (g1 && d1 <= tf1){
          int pos = atomicAdd(&scnt[1], 1);
          if (pos < TKCAP) cand[1*TKCAP + pos] = ((unsigned long long)fkey(d1) << 13) | (unsigned int)m;
        }
        if (g2 && d2 <= tf2){
          int pos = atomicAdd(&scnt[2], 1);
          if (pos < TKCAP) cand[2*TKCAP + pos] = ((unsigned long long)fkey(d2) << 13) | (unsigned int)m;
        }
        if (g3 && d3 <= tf3){
          int pos = atomicAdd(&scnt[3], 1);
          if (pos < TKCAP) cand[3*TKCAP + pos] = ((unsigned long long)fkey(d3) << 13) | (unsigned int)m;
        }
      }
    }
  }
  __syncthreads();

  // rank-count selection: wave wid handles row wid
  {
    int cnt = scnt[wid]; if (cnt > TKCAP) cnt = TKCAP;
    unsigned long long kv0 = (lane       < cnt) ? cand[wid*TKCAP + lane]       : ~0ull;
    unsigned long long kv1 = (lane + 64  < cnt) ? cand[wid*TKCAP + lane + 64]  : ~0ull;
    unsigned long long kv2 = (lane + 128 < cnt) ? cand[wid*TKCAP + lane + 128] : ~0ull;
    unsigned long long kv3 = (lane + 192 < cnt) ? cand[wid*TKCAP + lane + 192] : ~0ull;
    int r0=0, r1=0, r2=0, r3=0;
    for (int q2=0; q2<cnt; ++q2){
      unsigned long long cj = cand[wid*TKCAP + q2];
      r0 += (cj < kv0); r1 += (cj < kv1); r2 += (cj < kv2); r3 += (cj < kv3);
    }
    if (lane       < cnt && r0 < kk) sel[wid][r0] = (int)(kv0 & 8191ull);
    if (lane + 64  < cnt && r1 < kk) sel[wid][r1] = (int)(kv1 & 8191ull);
    if (lane + 128 < cnt && r2 < kk) sel[wid][r2] = (int)(kv2 & 8191ull);
    if (lane + 192 < cnt && r3 < kk) sel[wid][r3] = (int)(kv3 & 8191ull);
  }
  __syncthreads();

  // feature MSE over selected neighbors
  float mse = 0.f;
  int c = t & 127;
  int rh = t >> 7;
  for (int j=0;j<4;j++){
    int n = n0+j;
    if (n >= NN) break;           // uniform across block
    const float* f1n = feat1 + ((size_t)b*NN + n)*CC;
    float e = f1n[c];
    for (int r=rh; r<kk; r+=2){
      const float* g = feat1 + ((size_t)b*NN + sel[j][r])*CC;
      float d = g[c]-e;
      mse = fmaf(d,d,mse);
    }
  }

  float acc = wave_sum(mse);
  if (lane==0) rs[wid] = acc;
  __syncthreads();
  if (t==0){
    float s = (rs[0]+rs[1])+(rs[2]+rs[3]);
    atomicAdd(((double*)(ws+OFF_ACC)) + 128 + ((blockIdx.x + b) & 63), (double)s);
  }
}

// ---------------- proj2img stats (1024 threads) ----------------
__global__ __launch_bounds__(1024) void k_imgstats(const float* __restrict__ verts2, const float* __restrict__ imgoff,
                           float* __restrict__ ws) {
  __shared__ float r0[16], r1[16], r2[16], r3[16];
  __shared__ float sgs, smnx, smny;
  int img = blockIdx.x >> 2, b = blockIdx.x & 3;
  const float* pc = (img==0) ? (ws + OFF_V12 + (size_t)b*NN*3) : (verts2 + (size_t)b*NN*3);
  int lane = threadIdx.x & 63, wid = threadIdx.x >> 6;
  float mnx=INFINITY, mxx=-INFINITY, mny=INFINITY, mxy=-INFINITY;
  for (int n = threadIdx.x; n < NN; n += 1024) {
    float x = pc[(size_t)n*3], y = pc[(size_t)n*3+1];
    mnx=fminf(mnx,x); mxx=fmaxf(mxx,x); mny=fminf(mny,y); mxy=fmaxf(mxy,y);
  }
#pragma unroll
  for (int off=32; off; off>>=1) {
    mnx=fminf(mnx,__shfl_xor(mnx,off)); mxx=fmaxf(mxx,__shfl_xor(mxx,off));
    mny=fminf(mny,__shfl_xor(mny,off)); mxy=fmaxf(mxy,__shfl_xor(mxy,off));
  }
  if (lane==0){ r0[wid]=mnx; r1[wid]=mxx; r2[wid]=mny; r3[wid]=mxy; }
  __syncthreads();
  float* st = ws + OFF_STATS + (size_t)(img*4+b)*16;
  if (threadIdx.x==0){
    mnx=r0[0]; mxx=r1[0]; mny=r2[0]; mxy=r3[0];
    for (int i=1;i<16;i++){
      mnx=fminf(mnx,r0[i]); mxx=fmaxf(mxx,r1[i]);
      mny=fminf(mny,r2[i]); mxy=fmaxf(mxy,r3[i]);
    }
    float gs = fmaxf(mxx-mnx, mxy-mny) / 221.0f;
    sgs=gs; smnx=mnx; smny=mny;
    st[0]=mnx; st[1]=mxx; st[2]=mny; st[3]=mxy; st[4]=gs;
  }
  __syncthreads();
  float gs=sgs, bx=smnx, by=smny;
  float fmnx=INFINITY, fmxx=-INFINITY, fmny=INFINITY, fmxy=-INFINITY;
  for (int n = threadIdx.x; n < NN; n += 1024) {
    float fx = floorf((pc[(size_t)n*3]-bx)/gs);
    float fy = floorf((pc[(size_t)n*3+1]-by)/gs);
    fmnx=fminf(fmnx,fx); fmxx=fmaxf(fmxx,fx); fmny=fminf(fmny,fy); fmxy=fmaxf(fmxy,fy);
  }
#pragma unroll
  for (int off=32; off; off>>=1) {
    fmnx=fminf(fmnx,__shfl_xor(fmnx,off)); fmxx=fmaxf(fmxx,__shfl_xor(fmxx,off));
    fmny=fminf(fmny,__shfl_xor(fmny,off)); fmxy=fmaxf(fmxy,__shfl_xor(fmxy,off));
  }
  __syncthreads();
  if (lane==0){ r0[wid]=fmnx; r1[wid]=fmxx; r2[wid]=fmny; r3[wid]=fmxy; }
  __syncthreads();
  if (threadIdx.x==0){
    fmnx=r0[0]; fmxx=r1[0]; fmny=r2[0]; fmxy=r3[0];
    for (int i=1;i<16;i++){
      fmnx=fminf(fmnx,r0[i]); fmxx=fmaxf(fmxx,r1[i]);
      fmny=fminf(fmny,r2[i]); fmxy=fmaxf(fmxy,r3[i]);
    }
    float omnx=INFINITY, omxx=-INFINITY, omny=INFINITY, omxy=-INFINITY;
    for (int l=0;l<25;l++){
      float ox=imgoff[l*2], oy=imgoff[l*2+1];
      omnx=fminf(omnx,ox); omxx=fmaxf(omxx,ox); omny=fminf(omny,oy); omxy=fmaxf(omxy,oy);
    }
    float cx = floorf(((fmxx+omxx+1.0f)+(fmnx+omnx+1.0f))*0.5f);
    float cy = floorf(((fmxy+omxy+1.0f)+(fmny+omny+1.0f))*0.5f);
    st[5] = (112.0f - cx) - 1.0f;
    st[6] = (112.0f - cy) - 1.0f;
  }
}

// ---------------- scatter v1: 1 thread per (point,tap), replicated images ----------------
// v2 (5 taps/thread) measured +45us: serializing atomics per thread cut the
// memory-level parallelism the L2 atomic pipeline needs. Keep max TLP.
__global__ __launch_bounds__(256) void k_scatter(const float* __restrict__ verts2,
                          const float* __restrict__ imgoff,
                          float* __restrict__ ws, int nrep) {
  int g = blockIdx.x*256 + threadIdx.x;
  if (g >= NTAP) return;
  int p = g / 25; int l = g - p*25;
  int img = p / (BB*NN); int r = p - img*(BB*NN); int b = r / NN;
  const float* pc = (img==0) ? (ws + OFF_V12) : verts2;
  float x = pc[(size_t)r*3], y = pc[(size_t)r*3+1], z = pc[(size_t)r*3+2];
  const float* st = ws + OFF_STATS + (size_t)(img*4+b)*16;
  float mnx=st[0], mny=st[2], gs=st[4], offx=st[5], offy=st[6];
  float bx = floorf((x-mnx)/gs) + 1.0f + offx;
  float by = floorf((y-mny)/gs) + 1.0f + offy;
  float vx = bx + imgoff[l*2], vy = by + imgoff[l*2+1];
  vx += (vx<0.f?1.f:0.f) - (vx>223.f?1.f:0.f);
  vy += (vy<0.f?1.f:0.f) - (vy>223.f?1.f:0.f);
  vx = fminf(fmaxf(vx,0.f),223.f); vy = fminf(fmaxf(vy,0.f),223.f);
  int flat = (int)(vx*224.f + vy);
  float* im;
  if (nrep > 1)
    im = ws + OFF_IMGR + ((size_t)(((blockIdx.x & (nrep-1))*2 + img)*BB + b))*IMGP;
  else
    im = ws + (img==0?OFF_IMG1:OFF_IMG2) + (size_t)b*IMGP;
  atomicAdd(im + flat, z);
}

// ---------------- image loss (sums replicas) ----------------
__global__ void k_imgloss(float* __restrict__ ws, int nrep) {
  int i = blockIdx.x*blockDim.x + threadIdx.x;
  float v = 0.f;
  if (i < BB*IMGP) {
    float a, c;
    if (nrep > 1){
      a = 0.f; c = 0.f;
      for (int r=0; r<nrep; ++r){
        a += ws[OFF_IMGR + (size_t)(r*2+0)*BB*IMGP + i];
        c += ws[OFF_IMGR + (size_t)(r*2+1)*BB*IMGP + i];
      }
    } else {
      a = ws[OFF_IMG1+i]; c = ws[OFF_IMG2+i];
    }
    float sa = 1.f/(1.f+expf(-a)), sc = 1.f/(1.f+expf(-c));
    float d = sa - sc; v = d*d;
  }
  v = wave_sum(v);
  if ((threadIdx.x&63)==0)
    atomicAdd(((double*)(ws+OFF_ACC)) + 64 + (blockIdx.x & 63), (double)v);
}

// ---------------- finalize (64-thread wave reduce) ----------------
__global__ void k_final(const int* __restrict__ kptr, const float* __restrict__ ws, float* __restrict__ out) {
  const double* acc = (const double*)(ws+OFF_ACC);
  int t = threadIdx.x;
  double a0 = acc[t], a1 = acc[64+t], a2 = acc[128+t];
#pragma unroll
  for (int off=32; off; off>>=1){
    a0 += __shfl_down(a0, off);
    a1 += __shfl_down(a1, off);
    a2 += __shfl_down(a2, off);
  }
  if (t==0){
    int kk = *kptr; if (kk > 16) kk = 16; if (kk < 1) kk = 1;
    double srl = a0 / (double)(BB*NN);
    double img = a1 / ((double)BB*IMGP);
    double df  = a2 / ((double)BB*NN*kk*CC);
    out[0] = (float)(srl + img + df);
  }
}

extern "C" void kernel_launch(void* const* d_in, const int* in_sizes, int n_in,
                              void* d_out, int out_size, void* d_ws, size_t ws_size,
                              hipStream_t stream) {
  (void)in_sizes; (void)n_in; (void)out_size;
  const float* verts1 = (const float*)d_in[0];
  const float* verts2 = (const float*)d_in[1];
  const float* feat1  = (const float*)d_in[2];
  const float* feat2  = (const float*)d_in[3];
  const float* imgoff = (const float*)d_in[4];
  const int*   kptr   = (const int*)d_in[5];
  float* ws  = (float*)d_ws;
  float* out = (float*)d_out;
  int nrep = (ws_size >= WS_NEED_REP8) ? NREP8 : ((ws_size >= WS_NEED_REP) ? NREP : 1);

  if (nrep > 1){
    hipMemsetAsync(ws + OFF_ACC, 0, (size_t)ZERO2_FLOATS*sizeof(float), stream);
    hipMemsetAsync(ws + OFF_IMGR, 0, (size_t)nrep*2*BB*IMGP*sizeof(float), stream);
  } else {
    hipMemsetAsync(ws + ZERO_START, 0, (size_t)ZERO_FLOATS*sizeof(float), stream);
  }

  dim3 gC(NGP, BB);
  k_conv<<<gC, 256, 0, stream>>>(feat1, feat2, verts1, verts2, ws);

  dim3 gA(RBLK, SPLITS, BB);
  k_stageA<<<gA, 256, 0, stream>>>(feat1, ws);

  dim3 gS((NN+31)/32, BB);
  k_selfrec<<<gS, 256, 0, stream>>>(ws);

  dim3 gT((NN+3)/4, BB);
  k_topk<<<gT, 256, 0, stream>>>(feat1, kptr, ws);

  k_imgstats<<<8, 1024, 0, stream>>>(verts2, imgoff, ws);
  k_scatter<<<(NTAP+255)/256, 256, 0, stream>>>(verts2, imgoff, ws, nrep);
  k_imgloss<<<(BB*IMGP+255)/256, 256, 0, stream>>>(ws, nrep);

  k_final<<<1,64,0,stream>>>(kptr, ws, out);
}

// Round 15
// 307.552 us; speedup vs baseline: 1.1062x; 1.1062x over previous
//
#include <hip/hip_runtime.h>
#include <math.h>

#define BB 4
#define NN 4995
#define CC 128
#define IMG 224
#define IMGP (IMG*IMG)
#define ALPHA_F 100.0f
#define SPLITS 8
#define COLS_PER_SPLIT 640   // 32-aligned; 8*640=5120 >= 4995
#define RBLK 40              // ceil(4995/128)
#define NG 158               // col groups of 32 (incl. 1 pad group)
#define NGP 160              // c2q pad coverage groups
#define NCP 5120             // padded col count for c2q
#define NTAP (2*BB*NN*25)    // 999000 scatter taps
#define NREP 4
#define TKCAP 256            // per-row candidate cap (16-bit radix over-selects slightly)
#define GS_SELF ((NN+31)/32) // 157 selfrec blocks per batch
#define GS_TOPK ((NN+3)/4)   // 1249 topk blocks per batch

// softmax scale folding: (ALPHA * log2(e))^2 ; p = sqrt(SCALE*d) = ALPHA*log2e*sqrt(d)
#define SM_SCALE 20813.6898f
#define NEG2S   -41627.3796f
#define EPS_S    2.08136898e-8f   // 1e-12 * SM_SCALE

// ws layout in float units
#define OFF_V12    0            // 59940
#define OFF_FN1    60000        // 19980 (scaled by SM_SCALE)
#define OFF_V1Q    81000        // 79920 {x,y,z,|v1|^2}
#define OFF_V2Q    161000       // 79920 {x,y,z,|v2|^2}
#define OFF_C2Q    241000       // 81920 padded [b][5120] {x,y,z,SM_SCALE*|f2|^2}; pad={0,0,0,1e30}
#define OFF_PART   323000       // 19980*8*5 = 799200 -> ends 1122200
#define OFF_IMG1   1123000      // 200704
#define OFF_IMG2   1323704      // 200704 -> ends 1524408
#define OFF_ACC    1524408      // 3*64 f64 = 384 floats (byte 6097632, 8-aligned)
#define OFF_STATS  1524792      // 128 -> ends 1524920
#define OFF_F2H    1525000      // 4*158*4096 shorts = 1294336 floats
#define OFF_F2L    2820000      // 1294336 floats -> ends 4114336 (16.46MB)
#define OFF_IMGR   4115000      // 4 reps * 2 imgs * 4 b * 50176 = 1605632 floats -> ends 5720632
#define WS_NEED_REP ((size_t)5721000*sizeof(float))
#define ZERO_START OFF_IMG1
#define ZERO_FLOATS (1524920 - OFF_IMG1)
#define ZERO2_FLOATS (1524920 - OFF_ACC)   // ACC+STATS = 512

typedef short v8s  __attribute__((ext_vector_type(8)));
typedef float v16f __attribute__((ext_vector_type(16)));

#if __has_builtin(__builtin_amdgcn_exp2f)
__device__ __forceinline__ float fast_exp2(float x){ return __builtin_amdgcn_exp2f(x); }
#else
__device__ __forceinline__ float fast_exp2(float x){ float r; asm("v_exp_f32 %0, %1" : "=v"(r) : "v"(x)); return r; }
#endif
#if __has_builtin(__builtin_amdgcn_sqrtf)
__device__ __forceinline__ float fast_sqrt(float x){ return __builtin_amdgcn_sqrtf(x); }
#else
__device__ __forceinline__ float fast_sqrt(float x){ float r; asm("v_sqrt_f32 %0, %1" : "=v"(r) : "v"(x)); return r; }
#endif

__device__ __forceinline__ float wave_min(float v){
#pragma unroll
  for (int off=32; off; off>>=1) v = fminf(v, __shfl_xor(v, off));
  return v;
}
__device__ __forceinline__ float wave_sum(float v){
#pragma unroll
  for (int off=32; off; off>>=1) v += __shfl_xor(v, off);
  return v;
}

// pack top-16 bits (bf16 truncation) of two floats: (hi16(b)<<16)|hi16(a)
__device__ __forceinline__ int pack_bf_hi(float a, float b){
  return (int)__builtin_amdgcn_perm(__float_as_uint(b), __float_as_uint(a), 0x07060302u);
}

__device__ __forceinline__ void cvt_hilo(float4 a, float4 c, int4& hi, int4& lo){
  float hx=__uint_as_float(__float_as_uint(a.x)&0xffff0000u);
  float hy=__uint_as_float(__float_as_uint(a.y)&0xffff0000u);
  float hz=__uint_as_float(__float_as_uint(a.z)&0xffff0000u);
  float hw=__uint_as_float(__float_as_uint(a.w)&0xffff0000u);
  float gx=__uint_as_float(__float_as_uint(c.x)&0xffff0000u);
  float gy=__uint_as_float(__float_as_uint(c.y)&0xffff0000u);
  float gz=__uint_as_float(__float_as_uint(c.z)&0xffff0000u);
  float gw=__uint_as_float(__float_as_uint(c.w)&0xffff0000u);
  hi = make_int4(pack_bf_hi(a.x,a.y), pack_bf_hi(a.z,a.w),
                 pack_bf_hi(c.x,c.y), pack_bf_hi(c.z,c.w));
  lo = make_int4(pack_bf_hi(a.x-hx,a.y-hy), pack_bf_hi(a.z-hz,a.w-hw),
                 pack_bf_hi(c.x-gx,c.y-gy), pack_bf_hi(c.z-gz,c.w-gw));
}

__device__ __forceinline__ v8s i4_to_s8(int4 v){
  union { int4 i; v8s s; } u; u.i = v; return u.s;
}

// async global->LDS, 16B per lane, dest = wave-uniform base + lane*16
__device__ __forceinline__ void gld_lds16(const void* g, void* l){
  __builtin_amdgcn_global_load_lds((const __attribute__((address_space(1))) void*)g,
                                   (__attribute__((address_space(3))) void*)l, 16, 0, 0);
}

// monotone float->uint order map
__device__ __forceinline__ unsigned int fkey(float f){
  unsigned int u = __float_as_uint(f);
  return ((int)u < 0) ? ~u : (u ^ 0x80000000u);
}

// ---------------- fused: feat2->bf16 hi/lo tiles + c2q (+pads) + feat1 norms + vert quads ----------------
// tile layout [b][g][kt4][kh2][half2][c32][j8], strides (shorts): j=1,c32=8,half=256,kh=512,kt=1024,g=4096
__global__ __launch_bounds__(256) void k_conv(const float* __restrict__ feat1,
                                              const float* __restrict__ feat2,
                                              const float* __restrict__ verts1,
                                              const float* __restrict__ verts2,
                                              float* __restrict__ ws) {
  __shared__ float s2p[8][32], s1p[8][32];
  int g = blockIdx.x, b = blockIdx.y;
  int t = threadIdx.x;
  if (g >= NG){   // pure pad groups (158,159): only c2q pads
    if (t < 32){
      int c = g*32 + t;
      if (c < NCP)
        ((float4*)(ws+OFF_C2Q))[(size_t)b*NCP + c] = make_float4(0.f,0.f,0.f,1e30f);
    }
    return;
  }
  int q = t >> 5, c32 = t & 31;
  int col = g*32 + c32; if (col > NN-1) col = NN-1;
  const float4* src = (const float4*)(feat2 + ((size_t)(b*NN + col))*CC) + q*4;
  float4 v0 = src[0], v1 = src[1], v2 = src[2], v3 = src[3];
  {
    float s2 = 0.f;
    s2=fmaf(v0.x,v0.x,s2); s2=fmaf(v0.y,v0.y,s2); s2=fmaf(v0.z,v0.z,s2); s2=fmaf(v0.w,v0.w,s2);
    s2=fmaf(v1.x,v1.x,s2); s2=fmaf(v1.y,v1.y,s2); s2=fmaf(v1.z,v1.z,s2); s2=fmaf(v1.w,v1.w,s2);
    s2=fmaf(v2.x,v2.x,s2); s2=fmaf(v2.y,v2.y,s2); s2=fmaf(v2.z,v2.z,s2); s2=fmaf(v2.w,v2.w,s2);
    s2=fmaf(v3.x,v3.x,s2); s2=fmaf(v3.y,v3.y,s2); s2=fmaf(v3.z,v3.z,s2); s2=fmaf(v3.w,v3.w,s2);
    s2p[q][c32] = s2;
  }
  {
    const float4* fa = (const float4*)(feat1 + ((size_t)(b*NN + col))*CC) + q*4;
    float4 u0 = fa[0], u1 = fa[1], u2 = fa[2], u3 = fa[3];
    float s1 = 0.f;
    s1=fmaf(u0.x,u0.x,s1); s1=fmaf(u0.y,u0.y,s1); s1=fmaf(u0.z,u0.z,s1); s1=fmaf(u0.w,u0.w,s1);
    s1=fmaf(u1.x,u1.x,s1); s1=fmaf(u1.y,u1.y,s1); s1=fmaf(u1.z,u1.z,s1); s1=fmaf(u1.w,u1.w,s1);
    s1=fmaf(u2.x,u2.x,s1); s1=fmaf(u2.y,u2.y,s1); s1=fmaf(u2.z,u2.z,s1); s1=fmaf(u2.w,u2.w,s1);
    s1=fmaf(u3.x,u3.x,s1); s1=fmaf(u3.y,u3.y,s1); s1=fmaf(u3.z,u3.z,s1); s1=fmaf(u3.w,u3.w,s1);
    s1p[q][c32] = s1;
  }
  short* f2h = (short*)(ws + OFF_F2H);
  short* f2l = (short*)(ws + OFF_F2L);
  size_t base = ((size_t)(b*NG + g))*4096 + (size_t)q*512 + c32*8;
  int4 hi, lo;
  cvt_hilo(v0, v1, hi, lo);
  *(int4*)&f2h[base] = hi;  *(int4*)&f2l[base] = lo;
  cvt_hilo(v2, v3, hi, lo);
  *(int4*)&f2h[base + 256] = hi;  *(int4*)&f2l[base + 256] = lo;
  __syncthreads();
  if (t < 32){
    int c = g*32 + t;
    if (c < NN){
      float S2 = ((s2p[0][t]+s2p[1][t])+(s2p[2][t]+s2p[3][t]))
               + ((s2p[4][t]+s2p[5][t])+(s2p[6][t]+s2p[7][t]));
      float S1 = ((s1p[0][t]+s1p[1][t])+(s1p[2][t]+s1p[3][t]))
               + ((s1p[4][t]+s1p[5][t])+(s1p[6][t]+s1p[7][t]));
      size_t r = (size_t)(b*NN + c);
      float x=verts1[r*3], y=verts1[r*3+1], z=verts1[r*3+2];
      ((float4*)(ws+OFF_V1Q))[r] = make_float4(x,y,z, x*x+y*y+z*z);
      float x2=verts2[r*3], y2=verts2[r*3+1], z2=verts2[r*3+2];
      ((float4*)(ws+OFF_V2Q))[r] = make_float4(x2,y2,z2, x2*x2+y2*y2+z2*z2);
      ((float4*)(ws+OFF_C2Q))[(size_t)b*NCP + c] = make_float4(x2,y2,z2, SM_SCALE*S2);
      ws[OFF_FN1+r] = SM_SCALE*S1;
    } else if (c < NCP){
      ((float4*)(ws+OFF_C2Q))[(size_t)b*NCP + c] = make_float4(0.f,0.f,0.f,1e30f);
    }
  }
}

// ---------------- stage A: R7-champion structure (118.8us measured; R13 config) ----------------
__global__ __launch_bounds__(256) void k_stageA(const float* __restrict__ feat1,
      float* __restrict__ ws) {
  __shared__ __align__(16) short Bbuf[2][4096];   // per buf: Bh[0..2047] | Bl[2048..4095]
  __shared__ __align__(16) float colq[768*4];     // 640 used (+pad), {x,y,z,SM_SCALE*|f2|^2}

  int rblk  = blockIdx.x;
  int split = blockIdx.y;
  int b     = blockIdx.z;
  int rowBase = rblk*128;
  int colBase = split*COLS_PER_SPLIT;
  int colEnd  = colBase + COLS_PER_SPLIT; if (colEnd > NN) colEnd = NN;
  int nct = (colEnd - colBase + 63) >> 6;
  int nst = nct << 2;

  int t    = threadIdx.x;
  int w    = t >> 6;
  int lane = t & 63;
  int half = lane >> 5;
  int m32  = lane & 31;

  const float* f1b = feat1 + (size_t)b*NN*CC;
  const short* f2h = (const short*)(ws + OFF_F2H);
  const short* f2l = (const short*)(ws + OFF_F2L);
  const float4* cqb = (const float4*)(ws + OFF_C2Q) + (size_t)b*NCP;

#pragma unroll
  for (int r=0; r<3; r++){
    int col = colBase + r*256 + t; if (col > NCP-1) col = NCP-1;
    gld_lds16(cqb + col, &colq[(r*256 + w*64)*4]);
  }

  size_t f2base = (((size_t)(b*NG) + (colBase>>5) + (w>>1)) << 12) + (size_t)((t&127)*8);

  {
    short* d = &Bbuf[0][0] + w*512;
    gld_lds16(f2h + f2base, d);
    gld_lds16(f2l + f2base, d + 2048);
  }

  int nrow = rowBase + w*32 + m32;
  int nclamp = nrow > NN-1 ? NN-1 : nrow;
  float sn = ws[OFF_FN1 + (size_t)b*NN + nclamp];   // SM_SCALE*|f1|^2
  const float4* ar = (const float4*)(f1b + (size_t)nclamp*CC) + (half<<1);
  v8s Afh[8], Afl[8];   // slot = kt*2+kh
#pragma unroll
  for (int sl=0; sl<8; ++sl){
    float4 v0 = ar[sl*4], v1 = ar[sl*4+1];
    int4 hi, lo;
    cvt_hilo(v0, v1, hi, lo);
    Afh[sl] = i4_to_s8(hi); Afl[sl] = i4_to_s8(lo);
  }

  __syncthreads();   // drains vmcnt: colq + stage(0) complete for all waves

  float mm = INFINITY, S = 0.f, Vx = 0.f, Vy = 0.f, Vz = 0.f;

  for (int ci = 0; ci < nct; ci++){
    v16f acc0, acc1;
#pragma unroll
    for (int i=0;i<16;i++){ acc0[i]=0.f; acc1[i]=0.f; }

#pragma unroll
    for (int kt = 0; kt < 4; kt++){
      int s = (ci<<2) + kt;
      if (s+1 < nst){
        int s1 = s+1;
        size_t so = f2base + ((size_t)(s1>>2)<<13) + ((size_t)(s1&3)<<10);
        short* d = &Bbuf[0][0] + ((s1&1)<<12) + w*512;
        gld_lds16(f2h + so, d);
        gld_lds16(f2l + so, d + 2048);
      }
      const short* Bh = &Bbuf[0][0] + ((s&1)<<12);
      const short* Bl = Bh + 2048;
#pragma unroll
      for (int kh=0; kh<2; kh++){
        int fo = (kh<<9) + (half<<8) + (m32<<3);
        v8s a0h = *(const v8s*)&Bh[fo];
        v8s a0l = *(const v8s*)&Bl[fo];
        v8s a1h = *(const v8s*)&Bh[1024+fo];
        v8s a1l = *(const v8s*)&Bl[1024+fo];
        v8s b1h = Afh[kt*2+kh];
        v8s b1l = Afl[kt*2+kh];
        __builtin_amdgcn_s_setprio(1);
        acc0 = __builtin_amdgcn_mfma_f32_32x32x16_bf16(a0h, b1h, acc0, 0,0,0);
        acc0 = __builtin_amdgcn_mfma_f32_32x32x16_bf16(a0h, b1l, acc0, 0,0,0);
        acc0 = __builtin_amdgcn_mfma_f32_32x32x16_bf16(a0l, b1h, acc0, 0,0,0);
        acc1 = __builtin_amdgcn_mfma_f32_32x32x16_bf16(a1h, b1h, acc1, 0,0,0);
        acc1 = __builtin_amdgcn_mfma_f32_32x32x16_bf16(a1h, b1l, acc1, 0,0,0);
        acc1 = __builtin_amdgcn_mfma_f32_32x32x16_bf16(a1l, b1h, acc1, 0,0,0);
        __builtin_amdgcn_s_setprio(0);
      }
      __syncthreads();   // lgkm drained by MFMA deps; vmcnt(0)+barrier makes next buf ready
    }

    int cb4 = ci<<8;   // float index base into colq = ci*64*4
    float Mt = INFINITY;
#pragma unroll
    for (int reg=0; reg<16; reg++){
      int cp0 = (reg&3) + 8*(reg>>2) + 4*half;
      float f0 = colq[cb4 + cp0*4 + 3];
      float d0 = fmaf(NEG2S, acc0[reg], sn) + f0;
      float p0 = fast_sqrt(fmaxf(d0, EPS_S));
      acc0[reg] = p0; Mt = fminf(Mt, p0);
      float f1v = colq[cb4 + (cp0+32)*4 + 3];
      float d1 = fmaf(NEG2S, acc1[reg], sn) + f1v;
      float p1 = fast_sqrt(fmaxf(d1, EPS_S));
      acc1[reg] = p1; Mt = fminf(Mt, p1);
    }
    float mn = fminf(mm, Mt);
    float sc = fast_exp2(mn - mm);   // first tile: exp2(-inf) = 0
    float se=0.f, sx=0.f, sy=0.f, sz=0.f;
#pragma unroll
    for (int reg=0; reg<16; reg++){
      int cp0 = (reg&3) + 8*(reg>>2) + 4*half;
      float4 q0 = *(const float4*)&colq[cb4 + cp0*4];
      float e0 = fast_exp2(mn - acc0[reg]);
      se += e0; sx=fmaf(e0,q0.x,sx); sy=fmaf(e0,q0.y,sy); sz=fmaf(e0,q0.z,sz);
      float4 q1 = *(const float4*)&colq[cb4 + (cp0+32)*4];
      float e1 = fast_exp2(mn - acc1[reg]);
      se += e1; sx=fmaf(e1,q1.x,sx); sy=fmaf(e1,q1.y,sy); sz=fmaf(e1,q1.z,sz);
    }
    S  = fmaf(S,  sc, se);
    Vx = fmaf(Vx, sc, sx);
    Vy = fmaf(Vy, sc, sy);
    Vz = fmaf(Vz, sc, sz);
    mm = mn;
  }

  {
    float m2  = __shfl_xor(mm, 32);
    float S2  = __shfl_xor(S,  32);
    float Vx2 = __shfl_xor(Vx, 32);
    float Vy2 = __shfl_xor(Vy, 32);
    float Vz2 = __shfl_xor(Vz, 32);
    float M = fminf(mm, m2);
    float c1 = fast_exp2(M - mm), c2 = fast_exp2(M - m2);
    float Sf  = S*c1  + S2*c2;
    float Vxf = Vx*c1 + Vx2*c2;
    float Vyf = Vy*c1 + Vy2*c2;
    float Vzf = Vz*c1 + Vz2*c2;
    if (half==0 && nrow < NN){
      float* p = ws + OFF_PART + ((size_t)(b*NN+nrow)*SPLITS + split)*5;
      p[0]=M; p[1]=Sf; p[2]=Vxf; p[3]=Vyf; p[4]=Vzf;
    }
  }
}

// ---------------- merged tail: selfrec(+combine) blocks [0,157) | topk blocks [157,1406) ----------------
// Independent data: selfrec reads PART/V2Q, writes V12+ACC[0:64]; topk reads V1Q/feat1,
// writes ACC[128:192]. One grid lets their latency tails overlap and saves a launch.
#define TAIL_SMEM 12608
__global__ __launch_bounds__(256) void k_tail(const float* __restrict__ feat1,
        const int* __restrict__ kptr, float* __restrict__ ws) {
  __shared__ __align__(16) unsigned char sm[TAIL_SMEM];
  int t = threadIdx.x;
  int lane = t & 63, w = t >> 6;
  int b = blockIdx.y;

  if (blockIdx.x < GS_SELF) {
    // ---- selfrec body (R13-identical) ----
    float (*v12s)[3] = (float(*)[3])sm;
    int rblk = blockIdx.x;
    int r0blk = rblk*32;

    if (t < 32){
      int row = r0blk + t;
      int rowc = row > NN-1 ? NN-1 : row;
      const float* p = ws + OFF_PART + (size_t)(b*NN+rowc)*SPLITS*5;
      float mm = INFINITY;
#pragma unroll
      for (int s=0;s<SPLITS;s++) mm = fminf(mm, p[s*5]);
      float S=0.f,Vx=0.f,Vy=0.f,Vz=0.f;
#pragma unroll
      for (int s=0;s<SPLITS;s++){
        float sc = fast_exp2(mm - p[s*5]);
        S  += p[s*5+1]*sc; Vx += p[s*5+2]*sc; Vy += p[s*5+3]*sc; Vz += p[s*5+4]*sc;
      }
      float ox = Vx/S, oy = Vy/S, oz = Vz/S;
      v12s[t][0]=ox; v12s[t][1]=oy; v12s[t][2]=oz;
      if (row < NN){
        ws[OFF_V12+(size_t)(b*NN+row)*3+0]=ox;
        ws[OFF_V12+(size_t)(b*NN+row)*3+1]=oy;
        ws[OFF_V12+(size_t)(b*NN+row)*3+2]=oz;
      }
    }
    __syncthreads();

    int r0 = r0blk + w*8;
    const float4* v2q = (const float4*)(ws + OFF_V2Q) + (size_t)b*NN;
    float xr[8], yr[8], zr[8], sar[8]; bool val[8];
#pragma unroll
    for (int j=0;j<8;j++){
      int n = r0+j; val[j] = (n < NN);
      int li = w*8+j;
      float x=v12s[li][0], y=v12s[li][1], z=v12s[li][2];
      sar[j]=x*x+y*y+z*z;
      xr[j]=-2.0f*x; yr[j]=-2.0f*y; zr[j]=-2.0f*z;
    }
    float mn[8];
#pragma unroll
    for (int j=0;j<8;j++) mn[j] = INFINITY;
    for (int m=lane; m<NN; m+=64) {
      float4 q = v2q[m];
#pragma unroll
      for (int j=0;j<8;j++)
        mn[j] = fminf(mn[j], fmaf(xr[j],q.x, fmaf(yr[j],q.y, fmaf(zr[j],q.z, q.w))));
    }
    float s = 0.f;
#pragma unroll
    for (int j=0;j<8;j++){
      float v = wave_min(mn[j]);
      s += val[j] ? (v + sar[j]) : 0.f;
    }
    if (lane==0)
      atomicAdd(((double*)(ws+OFF_ACC)) + ((rblk*4 + w) & 63), (double)s);
    return;
  }

  // ---- topk body (R13-identical; tb replaces blockIdx.x) ----
  unsigned int* keybuf = (unsigned int*)sm;                       // 4*256 u32 = 4096B
  unsigned long long* cand = (unsigned long long*)(sm + 4096);    // 4*256 u64 = 8192B
  int* scnt = (int*)(sm + 12288);                                 // 16B
  float* tfs = (float*)(sm + 12304);                              // 16B
  int (*sel)[16] = (int(*)[16])(sm + 12320);                      // 256B
  float* rs = (float*)(sm + 12576);                               // 16B

  int wid = w;
  int tb = blockIdx.x - GS_SELF;
  int n0 = tb*4;
  int kk = *kptr; if (kk > 16) kk = 16; if (kk < 1) kk = 1;

  const float4* v1q = (const float4*)(ws + OFF_V1Q) + (size_t)b*NN;
  float mx[4], my2[4], mz[4];
#pragma unroll
  for (int j=0;j<4;j++){
    int n = n0+j; if (n > NN-1) n = NN-1;
    float4 me = v1q[n];
    mx[j]=-2.0f*me.x; my2[j]=-2.0f*me.y; mz[j]=-2.0f*me.z;
  }
  if (t < 4) scnt[t] = 0;

  float mn[4] = {INFINITY, INFINITY, INFINITY, INFINITY};
  for (int i=0;i<20;i++){
    int m = t + 256*i;
    if (m < NN){
      float4 q = v1q[m];
#pragma unroll
      for (int j=0;j<4;j++){
        float d = fmaf(mx[j], q.x, fmaf(my2[j], q.y, fmaf(mz[j], q.z, q.w)));
        mn[j] = fminf(mn[j], d);
      }
    }
  }

#pragma unroll
  for (int j=0;j<4;j++)
    keybuf[j*256 + t] = fkey(mn[j]) >> 16;
  __syncthreads();

  {
    unsigned int k0 = keybuf[wid*256 + lane];
    unsigned int k1 = keybuf[wid*256 + 64 + lane];
    unsigned int k2 = keybuf[wid*256 + 128 + lane];
    unsigned int k3 = keybuf[wid*256 + 192 + lane];
    unsigned int prefix = 0;
    for (int bit=15; bit>=0; --bit){
      unsigned int piv = prefix | (1u<<bit);
      int c = __popcll(__ballot(k0 < piv)) + __popcll(__ballot(k1 < piv))
            + __popcll(__ballot(k2 < piv)) + __popcll(__ballot(k3 < piv));
      if (c < kk) prefix = piv;
    }
    unsigned int K = (prefix<<16) | 0xFFFFu;     // full-key upper bound for the bucket
    unsigned int fb = (K & 0x80000000u) ? (K ^ 0x80000000u) : ~K;
    if (lane==0) tfs[wid] = __uint_as_float(fb);
  }
  __syncthreads();
  float tf0 = tfs[0], tf1 = tfs[1], tf2 = tfs[2], tf3 = tfs[3];

  bool g0 = (mn[0] <= tf0), g1 = (mn[1] <= tf1), g2 = (mn[2] <= tf2), g3 = (mn[3] <= tf3);
  if (g0|g1|g2|g3){
    for (int i=0;i<20;i++){
      int m = t + 256*i;
      if (m < NN){
        float4 q = v1q[m];
        float sw = q.w;
        float d0 = fmaf(mx[0], q.x, fmaf(my2[0], q.y, fmaf(mz[0], q.z, sw)));
        float d1 = fmaf(mx[1], q.x, fmaf(my2[1], q.y, fmaf(mz[1], q.z, sw)));
        float d2 = fmaf(mx[2], q.x, fmaf(my2[2], q.y, fmaf(mz[2], q.z, sw)));
        float d3 = fmaf(mx[3], q.x, fmaf(my2[3], q.y, fmaf(mz[3], q.z, sw)));
        if (g0 && d0 <= tf0){
          int pos = atomicAdd(&scnt[0], 1);
          if (pos < TKCAP) cand[0*TKCAP + pos] = ((unsigned long long)fkey(d0) << 13) | (unsigned int)m;
        }
        if (g1 && d1 <= tf1){
          int pos = atomicAdd(&scnt[1], 1);
          if (pos < TKCAP) cand[1*TKCAP + pos] = ((unsigned long long)fkey(d1) << 13) | (unsigned int)m;
        }
        if (g2 && d2 <= tf2){
          int pos = atomicAdd(&scnt[2], 1);
          if (pos < TKCAP) cand[2*TKCAP + pos] = ((unsigned long long)fkey(d2) << 13) | (unsigned int)m;
        }
        if (g3 && d3 <= tf3){
          int pos = atomicAdd(&scnt[3], 1);
          if (pos < TKCAP) cand[3*TKCAP + pos] = ((unsigned long long)fkey(d3) << 13) | (unsigned int)m;
        }
      }
    }
  }
  __syncthreads();

  {
    int cnt = scnt[wid]; if (cnt > TKCAP) cnt = TKCAP;
    unsigned long long kv0 = (lane       < cnt) ? cand[wid*TKCAP + lane]       : ~0ull;
    unsigned long long kv1 = (lane + 64  < cnt) ? cand[wid*TKCAP + lane + 64]  : ~0ull;
    unsigned long long kv2 = (lane + 128 < cnt) ? cand[wid*TKCAP + lane + 128] : ~0ull;
    unsigned long long kv3 = (lane + 192 < cnt) ? cand[wid*TKCAP + lane + 192] : ~0ull;
    int r0=0, r1=0, r2=0, r3=0;
    for (int q2=0; q2<cnt; ++q2){
      unsigned long long cj = cand[wid*TKCAP + q2];
      r0 += (cj < kv0); r1 += (cj < kv1); r2 += (cj < kv2); r3 += (cj < kv3);
    }
    if (lane       < cnt && r0 < kk) sel[wid][r0] = (int)(kv0 & 8191ull);
    if (lane + 64  < cnt && r1 < kk) sel[wid][r1] = (int)(kv1 & 8191ull);
    if (lane + 128 < cnt && r2 < kk) sel[wid][r2] = (int)(kv2 & 8191ull);
    if (lane + 192 < cnt && r3 < kk) sel[wid][r3] = (int)(kv3 & 8191ull);
  }
  __syncthreads();

  float mse = 0.f;
  int c = t & 127;
  int rh = t >> 7;
  for (int j=0;j<4;j++){
    int n = n0+j;
    if (n >= NN) break;           // uniform across block
    const float* f1n = feat1 + ((size_t)b*NN + n)*CC;
    float e = f1n[c];
    for (int r=rh; r<kk; r+=2){
      const float* g = feat1 + ((size_t)b*NN + sel[j][r])*CC;
      float d = g[c]-e;
      mse = fmaf(d,d,mse);
    }
  }

  float acc = wave_sum(mse);
  if (lane==0) rs[wid] = acc;
  __syncthreads();
  if (t==0){
    float s = (rs[0]+rs[1])+(rs[2]+rs[3]);
    atomicAdd(((double*)(ws+OFF_ACC)) + 128 + ((tb + b) & 63), (double)s);
  }
}

// ---------------- proj2img stats (1024 threads) ----------------
__global__ __launch_bounds__(1024) void k_imgstats(const float* __restrict__ verts2, const float* __restrict__ imgoff,
                           float* __restrict__ ws) {
  __shared__ float r0[16], r1[16], r2[16], r3[16];
  __shared__ float sgs, smnx, smny;
  int img = blockIdx.x >> 2, b = blockIdx.x & 3;
  const float* pc = (img==0) ? (ws + OFF_V12 + (size_t)b*NN*3) : (verts2 + (size_t)b*NN*3);
  int lane = threadIdx.x & 63, wid = threadIdx.x >> 6;
  float mnx=INFINITY, mxx=-INFINITY, mny=INFINITY, mxy=-INFINITY;
  for (int n = threadIdx.x; n < NN; n += 1024) {
    float x = pc[(size_t)n*3], y = pc[(size_t)n*3+1];
    mnx=fminf(mnx,x); mxx=fmaxf(mxx,x); mny=fminf(mny,y); mxy=fmaxf(mxy,y);
  }
#pragma unroll
  for (int off=32; off; off>>=1) {
    mnx=fminf(mnx,__shfl_xor(mnx,off)); mxx=fmaxf(mxx,__shfl_xor(mxx,off));
    mny=fminf(mny,__shfl_xor(mny,off)); mxy=fmaxf(mxy,__shfl_xor(mxy,off));
  }
  if (lane==0){ r0[wid]=mnx; r1[wid]=mxx; r2[wid]=mny; r3[wid]=mxy; }
  __syncthreads();
  float* st = ws + OFF_STATS + (size_t)(img*4+b)*16;
  if (threadIdx.x==0){
    mnx=r0[0]; mxx=r1[0]; mny=r2[0]; mxy=r3[0];
    for (int i=1;i<16;i++){
      mnx=fminf(mnx,r0[i]); mxx=fmaxf(mxx,r1[i]);
      mny=fminf(mny,r2[i]); mxy=fmaxf(mxy,r3[i]);
    }
    float gs = fmaxf(mxx-mnx, mxy-mny) / 221.0f;
    sgs=gs; smnx=mnx; smny=mny;
    st[0]=mnx; st[1]=mxx; st[2]=mny; st[3]=mxy; st[4]=gs;
  }
  __syncthreads();
  float gs=sgs, bx=smnx, by=smny;
  float fmnx=INFINITY, fmxx=-INFINITY, fmny=INFINITY, fmxy=-INFINITY;
  for (int n = threadIdx.x; n < NN; n += 1024) {
    float fx = floorf((pc[(size_t)n*3]-bx)/gs);
    float fy = floorf((pc[(size_t)n*3+1]-by)/gs);
    fmnx=fminf(fmnx,fx); fmxx=fmaxf(fmxx,fx); fmny=fminf(fmny,fy); fmxy=fmaxf(fmxy,fy);
  }
#pragma unroll
  for (int off=32; off; off>>=1) {
    fmnx=fminf(fmnx,__shfl_xor(fmnx,off)); fmxx=fmaxf(fmxx,__shfl_xor(fmxx,off));
    fmny=fminf(fmny,__shfl_xor(fmny,off)); fmxy=fmaxf(fmxy,__shfl_xor(fmxy,off));
  }
  __syncthreads();
  if (lane==0){ r0[wid]=fmnx; r1[wid]=fmxx; r2[wid]=fmny; r3[wid]=fmxy; }
  __syncthreads();
  if (threadIdx.x==0){
    fmnx=r0[0]; fmxx=r1[0]; fmny=r2[0]; fmxy=r3[0];
    for (int i=1;i<16;i++){
      fmnx=fminf(fmnx,r0[i]); fmxx=fmaxf(fmxx,r1[i]);
      fmny=fminf(fmny,r2[i]); fmxy=fmaxf(fmxy,r3[i]);
    }
    float omnx=INFINITY, omxx=-INFINITY, omny=INFINITY, omxy=-INFINITY;
    for (int l=0;l<25;l++){
      float ox=imgoff[l*2], oy=imgoff[l*2+1];
      omnx=fminf(omnx,ox); omxx=fmaxf(omxx,ox); omny=fminf(omny,oy); omxy=fmaxf(omxy,oy);
    }
    float cx = floorf(((fmxx+omxx+1.0f)+(fmnx+omnx+1.0f))*0.5f);
    float cy = floorf(((fmxy+omxy+1.0f)+(fmny+omny+1.0f))*0.5f);
    st[5] = (112.0f - cx) - 1.0f;
    st[6] = (112.0f - cy) - 1.0f;
  }
}

// ---------------- scatter v1: 1 thread per (point,tap), replicated images ----------------
__global__ __launch_bounds__(256) void k_scatter(const float* __restrict__ verts2,
                          const float* __restrict__ imgoff,
                          float* __restrict__ ws, int nrep) {
  int g = blockIdx.x*256 + threadIdx.x;
  if (g >= NTAP) return;
  int p = g / 25; int l = g - p*25;
  int img = p / (BB*NN); int r = p - img*(BB*NN); int b = r / NN;
  const float* pc = (img==0) ? (ws + OFF_V12) : verts2;
  float x = pc[(size_t)r*3], y = pc[(size_t)r*3+1], z = pc[(size_t)r*3+2];
  const float* st = ws + OFF_STATS + (size_t)(img*4+b)*16;
  float mnx=st[0], mny=st[2], gs=st[4], offx=st[5], offy=st[6];
  float bx = floorf((x-mnx)/gs) + 1.0f + offx;
  float by = floorf((y-mny)/gs) + 1.0f + offy;
  float vx = bx + imgoff[l*2], vy = by + imgoff[l*2+1];
  vx += (vx<0.f?1.f:0.f) - (vx>223.f?1.f:0.f);
  vy += (vy<0.f?1.f:0.f) - (vy>223.f?1.f:0.f);
  vx = fminf(fmaxf(vx,0.f),223.f); vy = fminf(fmaxf(vy,0.f),223.f);
  int flat = (int)(vx*224.f + vy);
  float* im;
  if (nrep > 1)
    im = ws + OFF_IMGR + ((size_t)(((blockIdx.x & (nrep-1))*2 + img)*BB + b))*IMGP;
  else
    im = ws + (img==0?OFF_IMG1:OFF_IMG2) + (size_t)b*IMGP;
  atomicAdd(im + flat, z);
}

// ---------------- image loss (sums replicas) ----------------
__global__ void k_imgloss(float* __restrict__ ws, int nrep) {
  int i = blockIdx.x*blockDim.x + threadIdx.x;
  float v = 0.f;
  if (i < BB*IMGP) {
    float a, c;
    if (nrep > 1){
      a = 0.f; c = 0.f;
      for (int r=0; r<nrep; ++r){
        a += ws[OFF_IMGR + (size_t)(r*2+0)*BB*IMGP + i];
        c += ws[OFF_IMGR + (size_t)(r*2+1)*BB*IMGP + i];
      }
    } else {
      a = ws[OFF_IMG1+i]; c = ws[OFF_IMG2+i];
    }
    float sa = 1.f/(1.f+expf(-a)), sc = 1.f/(1.f+expf(-c));
    float d = sa - sc; v = d*d;
  }
  v = wave_sum(v);
  if ((threadIdx.x&63)==0)
    atomicAdd(((double*)(ws+OFF_ACC)) + 64 + (blockIdx.x & 63), (double)v);
}

// ---------------- finalize (64-thread wave reduce) ----------------
__global__ void k_final(const int* __restrict__ kptr, const float* __restrict__ ws, float* __restrict__ out) {
  const double* acc = (const double*)(ws+OFF_ACC);
  int t = threadIdx.x;
  double a0 = acc[t], a1 = acc[64+t], a2 = acc[128+t];
#pragma unroll
  for (int off=32; off; off>>=1){
    a0 += __shfl_down(a0, off);
    a1 += __shfl_down(a1, off);
    a2 += __shfl_down(a2, off);
  }
  if (t==0){
    int kk = *kptr; if (kk > 16) kk = 16; if (kk < 1) kk = 1;
    double srl = a0 / (double)(BB*NN);
    double img = a1 / ((double)BB*IMGP);
    double df  = a2 / ((double)BB*NN*kk*CC);
    out[0] = (float)(srl + img + df);
  }
}

extern "C" void kernel_launch(void* const* d_in, const int* in_sizes, int n_in,
                              void* d_out, int out_size, void* d_ws, size_t ws_size,
                              hipStream_t stream) {
  (void)in_sizes; (void)n_in; (void)out_size;
  const float* verts1 = (const float*)d_in[0];
  const float* verts2 = (const float*)d_in[1];
  const float* feat1  = (const float*)d_in[2];
  const float* feat2  = (const float*)d_in[3];
  const float* imgoff = (const float*)d_in[4];
  const int*   kptr   = (const int*)d_in[5];
  float* ws  = (float*)d_ws;
  float* out = (float*)d_out;
  int nrep = (ws_size >= WS_NEED_REP) ? NREP : 1;

  if (nrep > 1){
    hipMemsetAsync(ws + OFF_ACC, 0, (size_t)ZERO2_FLOATS*sizeof(float), stream);
    hipMemsetAsync(ws + OFF_IMGR, 0, (size_t)NREP*2*BB*IMGP*sizeof(float), stream);
  } else {
    hipMemsetAsync(ws + ZERO_START, 0, (size_t)ZERO_FLOATS*sizeof(float), stream);
  }

  dim3 gC(NGP, BB);
  k_conv<<<gC, 256, 0, stream>>>(feat1, feat2, verts1, verts2, ws);

  dim3 gA(RBLK, SPLITS, BB);
  k_stageA<<<gA, 256, 0, stream>>>(feat1, ws);

  dim3 gT(GS_SELF + GS_TOPK, BB);
  k_tail<<<gT, 256, 0, stream>>>(feat1, kptr, ws);

  k_imgstats<<<8, 1024, 0, stream>>>(verts2, imgoff, ws);
  k_scatter<<<(NTAP+255)/256, 256, 0, stream>>>(verts2, imgoff, ws, nrep);
  k_imgloss<<<(BB*IMGP+255)/256, 256, 0, stream>>>(ws, nrep);

  k_final<<<1,64,0,stream>>>(kptr, ws, out);
}